// Round 2
// baseline (374.211 us; speedup 1.0000x reference)
//
#include <hip/hip_runtime.h>

// B=8, N=256, D=128
// out[b,i,d] = sum_e T[b,i,e]*W[e,d] + bias[d]
//   T[b,i,e]  = sum_j adj[b,i,j] * (hidden[b,j,e] + dep[b,j,i,e])
//
// Split-K over j so each block streams CONTIGUOUS dep memory (v1's per-block
// 128 KB power-of-2 stride walk serialized on L2 sets/DRAM banks -> 0.75 TB/s).
// K1: block=(b, j-chunk 16, i-tile 32), register accumulation, writes partials
//     P[b,i,ch,e] to d_ws (16.8 MB). K2: chunk-reduce + 128x128 matvec + bias.

constexpr int Bc  = 8;
constexpr int Nc  = 256;
constexpr int Dc  = 128;
constexpr int JC  = 16;          // j per chunk
constexpr int NCH = Nc / JC;     // 16 chunks
constexpr int IT  = 32;          // i per block
constexpr int NIQ = Nc / IT;     // 8 i-tiles

__global__ __launch_bounds__(256) void depgcn_k1(
    const float* __restrict__ hidden,  // [B,N,D]
    const float* __restrict__ adj,     // [B,N,N]
    const float* __restrict__ dep,     // [B,N,N,D]
    float* __restrict__ P)             // [B,N,NCH,D] partials
{
    const int blk = blockIdx.x;        // 0 .. 1023
    const int iq  = blk & (NIQ - 1);
    const int jc  = (blk >> 3) & (NCH - 1);
    const int b   = blk >> 7;
    const int t   = threadIdx.x;       // 0..255
    const int g   = t >> 5;            // group 0..7 (owns i_local g*4..g*4+3)
    const int c   = t & 31;            // e = 4c..4c+3

    __shared__ float sH[JC][Dc];       // 8 KB: hidden chunk
    __shared__ float sA[IT][JC];       // 2 KB: adj tile

    // stage hidden[b, jc*JC + row, :]  (8 floats/thread)
    {
        const int row = t >> 4;            // 0..15
        const int col = (t & 15) * 8;      // 0..120
        const float* hp = hidden + ((size_t)b * Nc + jc * JC + row) * Dc + col;
        *(float4*)&sH[row][col]     = *(const float4*)hp;
        *(float4*)&sH[row][col + 4] = *(const float4*)(hp + 4);
    }
    // stage adj[b, iq*IT + iL, jc*JC + jL..jL+1]  (2 floats/thread)
    {
        const int iL = t >> 3;             // 0..31
        const int jL = (t & 7) * 2;        // 0,2,..,14
        const float* ap = adj + ((size_t)b * Nc + iq * IT + iL) * Nc + jc * JC + jL;
        sA[iL][jL]     = ap[0];
        sA[iL][jL + 1] = ap[1];
    }
    __syncthreads();

    float4 acc[4];
    #pragma unroll
    for (int ii = 0; ii < 4; ++ii) acc[ii] = make_float4(0.f, 0.f, 0.f, 0.f);

    // dep[b, jc*JC + j, iq*IT + g*4 + ii, 4c..]
    const float* depB = dep +
        ((((size_t)b * Nc + jc * JC) * Nc) + iq * IT + g * 4) * Dc + (size_t)c * 4;

    #pragma unroll 2
    for (int j = 0; j < JC; ++j) {
        const float4 h4 = *(const float4*)&sH[j][c * 4];
        const float* dj = depB + (size_t)j * Nc * Dc;
        #pragma unroll
        for (int ii = 0; ii < 4; ++ii) {
            const float  a  = sA[g * 4 + ii][j];
            const float4 d4 = *(const float4*)(dj + (size_t)ii * Dc);
            acc[ii].x = fmaf(a, d4.x + h4.x, acc[ii].x);
            acc[ii].y = fmaf(a, d4.y + h4.y, acc[ii].y);
            acc[ii].z = fmaf(a, d4.z + h4.z, acc[ii].z);
            acc[ii].w = fmaf(a, d4.w + h4.w, acc[ii].w);
        }
    }

    // P[b, i_g, jc, e]
    #pragma unroll
    for (int ii = 0; ii < 4; ++ii) {
        const int ig = iq * IT + g * 4 + ii;
        float* pp = P + (((size_t)b * Nc + ig) * NCH + jc) * Dc + (size_t)c * 4;
        *(float4*)pp = acc[ii];
    }
}

__global__ __launch_bounds__(256) void depgcn_k2(
    const float* __restrict__ P,       // [B,N,NCH,D]
    const float* __restrict__ W,       // [D,D]
    const float* __restrict__ bias,    // [D]
    float* __restrict__ out)           // [B,N,D]
{
    const int bi = blockIdx.x;         // (b,i)
    const int b  = bi >> 8;
    const int i  = bi & (Nc - 1);
    const int t  = threadIdx.x;

    __shared__ float sT[Dc];
    __shared__ float sO[2][Dc];

    if (t < Dc) {
        const float* pp = P + ((size_t)b * Nc + i) * NCH * Dc + t;
        float s = 0.f;
        #pragma unroll
        for (int ch = 0; ch < NCH; ++ch) s += pp[(size_t)ch * Dc];
        sT[t] = s;
    }
    __syncthreads();

    {
        const int d = t & (Dc - 1);
        const int h = t >> 7;
        const float* wp = W + (size_t)(h * 64) * Dc + d;
        float s = 0.f;
        #pragma unroll 8
        for (int e = 0; e < 64; ++e)
            s = fmaf(sT[h * 64 + e], wp[(size_t)e * Dc], s);
        sO[h][d] = s;
    }
    __syncthreads();

    if (t < Dc) {
        out[((size_t)b * Nc + i) * Dc + t] = sO[0][t] + sO[1][t] + bias[t];
    }
}

extern "C" void kernel_launch(void* const* d_in, const int* in_sizes, int n_in,
                              void* d_out, int out_size, void* d_ws, size_t ws_size,
                              hipStream_t stream) {
    const float* hidden = (const float*)d_in[0];
    const float* adj    = (const float*)d_in[1];
    const float* dep    = (const float*)d_in[2];
    const float* W      = (const float*)d_in[3];
    const float* bias   = (const float*)d_in[4];
    float* out          = (float*)d_out;
    float* P            = (float*)d_ws;   // needs B*N*NCH*D*4 = 16.8 MB

    depgcn_k1<<<dim3(Bc * NCH * NIQ), dim3(256), 0, stream>>>(hidden, adj, dep, P);
    depgcn_k2<<<dim3(Bc * Nc), dim3(256), 0, stream>>>(P, W, bias, out);
}